// Round 14
// baseline (124.538 us; speedup 1.0000x reference)
//
#include <hip/hip_runtime.h>

// DynamicDifferentiablePalette — CALIBRATION ROUND.
// Rounds 6/8/9 (VMEM fetch / s_load fetch / 4px-thread, 4x fewer fetches)
// all timed 84-86 us => dur_us is dominated by a fixed component we can't
// see (top-5 dispatches are all 268MB harness poison fills at ~43 us).
// This round runs the identical round-9 kernel but executes the inner K-loop
// REPEAT=4 times (asm value barriers defeat CSE; output = (4*Swa)/(4*Sw) is
// mathematically unchanged). dur delta / 3 = true inner-loop duration.

#define BATCH 16
#define HW 65536
#define KMAX 64
#define BLOCKS_PER_IMG 64   // 65536 / (256 threads * 4 px)
#define REPEAT 4

__global__ __launch_bounds__(64) void coef_kernel(
    const float* __restrict__ palettes,
    const float* __restrict__ temperature,
    float4*      __restrict__ cf)
{
    const int b = blockIdx.x;
    const int k = threadIdx.x;
    const float scale = 1.4426950408889634f / temperature[0];   // log2(e)/T

    const float pr = palettes[(b * KMAX + k) * 3 + 0];
    const float pg = palettes[(b * KMAX + k) * 3 + 1];
    const float pb = palettes[(b * KMAX + k) * 3 + 2];

    float4 q;
    q.x = 2.0f * pr * scale;
    q.y = 2.0f * pg * scale;
    q.z = 2.0f * pb * scale;
    q.w = (-(pr * pr + pg * pg + pb * pb) - 3.0f) * scale;  // -3/T shift
    cf[b * KMAX + k] = q;
}

__global__ __launch_bounds__(256) void palette_blend_kernel(
    const float* __restrict__ images,
    const int*   __restrict__ palette_sizes,
    const float* __restrict__ temperature,
    const float4* __restrict__ cf,
    float*       __restrict__ out)
{
    const int b    = blockIdx.x >> 6;
    const int blk  = blockIdx.x & (BLOCKS_PER_IMG - 1);
    const int pix0 = (blk << 10) + (threadIdx.x << 2);
    const int K    = palette_sizes[b];

    const long base = (long)b * (HW * 3) + (long)pix0 * 3;
    const float4 v0 = *(const float4*)(images + base + 0);
    const float4 v1 = *(const float4*)(images + base + 4);
    const float4 v2 = *(const float4*)(images + base + 8);

    const float xA0 = v0.x, xA1 = v0.y, xA2 = v0.z;
    const float xB0 = v0.w, xB1 = v1.x, xB2 = v1.y;
    const float xC0 = v1.z, xC1 = v1.w, xC2 = v2.x;
    const float xD0 = v2.y, xD1 = v2.z, xD2 = v2.w;

    const float4* __restrict__ c4 = cf + b * KMAX;

    float sA = 0.f, aA0 = 0.f, aA1 = 0.f, aA2 = 0.f;
    float sB = 0.f, aB0 = 0.f, aB1 = 0.f, aB2 = 0.f;
    float sC = 0.f, aC0 = 0.f, aC1 = 0.f, aC2 = 0.f;
    float sD = 0.f, aD0 = 0.f, aD1 = 0.f, aD2 = 0.f;

    for (int r = 0; r < REPEAT; ++r) {
        // Opaque copies of the pixel values: value-numbering cannot merge
        // the 4 repeats, so the full K-loop executes 4x (calibration).
        float y0 = xA0, y1 = xA1, y2 = xA2, y3 = xB0, y4 = xB1, y5 = xB2,
              y6 = xC0, y7 = xC1, y8 = xC2, y9 = xD0, yA = xD1, yB = xD2;
        asm volatile("" : "+v"(y0), "+v"(y1), "+v"(y2), "+v"(y3),
                          "+v"(y4), "+v"(y5), "+v"(y6), "+v"(y7),
                          "+v"(y8), "+v"(y9), "+v"(yA), "+v"(yB));
        #pragma unroll 2
        for (int k = 0; k < K; ++k) {
            const float4 A = c4[k];
            const float lA = fmaf(A.x, y0, fmaf(A.y, y1, fmaf(A.z, y2, A.w)));
            const float lB = fmaf(A.x, y3, fmaf(A.y, y4, fmaf(A.z, y5, A.w)));
            const float lC = fmaf(A.x, y6, fmaf(A.y, y7, fmaf(A.z, y8, A.w)));
            const float lD = fmaf(A.x, y9, fmaf(A.y, yA, fmaf(A.z, yB, A.w)));
            const float wA = exp2f(lA), wB = exp2f(lB), wC = exp2f(lC), wD = exp2f(lD);
            sA += wA; aA0 = fmaf(wA, A.x, aA0); aA1 = fmaf(wA, A.y, aA1); aA2 = fmaf(wA, A.z, aA2);
            sB += wB; aB0 = fmaf(wB, A.x, aB0); aB1 = fmaf(wB, A.y, aB1); aB2 = fmaf(wB, A.z, aB2);
            sC += wC; aC0 = fmaf(wC, A.x, aC0); aC1 = fmaf(wC, A.y, aC1); aC2 = fmaf(wC, A.z, aC2);
            sD += wD; aD0 = fmaf(wD, A.x, aD0); aD1 = fmaf(wD, A.y, aD1); aD2 = fmaf(wD, A.z, aD2);
        }
    }

    const float scale = 1.4426950408889634f / temperature[0];
    const float h = 0.5f / scale;                 // undo a = 2*scale*p
    const float iA = h / sA, iB = h / sB, iC = h / sC, iD = h / sD;

    float4 o0, o1, o2;
    o0.x = aA0 * iA; o0.y = aA1 * iA; o0.z = aA2 * iA;
    o0.w = aB0 * iB; o1.x = aB1 * iB; o1.y = aB2 * iB;
    o1.z = aC0 * iC; o1.w = aC1 * iC; o2.x = aC2 * iC;
    o2.y = aD0 * iD; o2.z = aD1 * iD; o2.w = aD2 * iD;

    *(float4*)(out + base + 0) = o0;
    *(float4*)(out + base + 4) = o1;
    *(float4*)(out + base + 8) = o2;
}

extern "C" void kernel_launch(void* const* d_in, const int* in_sizes, int n_in,
                              void* d_out, int out_size, void* d_ws, size_t ws_size,
                              hipStream_t stream) {
    const float* images        = (const float*)d_in[0];
    const float* palettes      = (const float*)d_in[1];
    const int*   palette_sizes = (const int*)d_in[2];
    const float* temperature   = (const float*)d_in[3];
    float*       out           = (float*)d_out;
    float4*      cf            = (float4*)d_ws;   // 16 KB

    coef_kernel<<<dim3(BATCH), dim3(KMAX), 0, stream>>>(palettes, temperature, cf);
    palette_blend_kernel<<<dim3(BATCH * BLOCKS_PER_IMG), dim3(256), 0, stream>>>(
        images, palette_sizes, temperature, cf, out);
}

// Round 17
// 82.333 us; speedup vs baseline: 1.5126x; 1.5126x over previous
//
#include <hip/hip_runtime.h>

// DynamicDifferentiablePalette: per-pixel softmax-weighted palette blend.
// images [16,256,256,3] f32, palettes [16,64,3] f32, palette_sizes [16] i32,
// temperature f32 -> out [16,256,256,3] f32.
//
// Round-15 (post-calibration): kernel=25us of dur=85 (harness floor ~60us).
// Loop=13.2us vs 4.7us VALU floor; gap = occupancy 23% + ragged-K imbalance
// (4 K-draws/CU -> +-28%) + separate coef dispatch.
//  - ONE fused kernel: block computes its image's 64 coef quads into LDS
//    (1KB), then 4px/thread loop with one broadcast ds_read_b128 per k.
//  - 4096 blocks x 64 thr: 256 contiguous blocks/image + round-robin
//    dispatch => each CU gets one block of EVERY image => per-CU work
//    = Sum(K_b) uniformly => no tail. 16 waves/CU resident.
//  - math: logit=(2p.x-||p||^2-3)*log2e/T; w=exp2f; accumulate Sum(w*a),
//    a=2*log2e/T*p; epilogue divides by 2*log2e/T. exp2 args in [-8.7,4.4].

#define BATCH 16
#define HW 65536
#define KMAX 64
#define THREADS 64
#define PX 4
#define BLOCKS_PER_IMG (HW / (THREADS * PX))   // 256

__global__ __launch_bounds__(THREADS) void palette_blend_kernel(
    const float* __restrict__ images,
    const float* __restrict__ palettes,
    const int*   __restrict__ palette_sizes,
    const float* __restrict__ temperature,
    float*       __restrict__ out)
{
    __shared__ float4 cc[KMAX];   // {a0,a1,a2,c} per palette entry

    const int b   = blockIdx.x >> 8;                    // image (256 blocks/img)
    const int blk = blockIdx.x & (BLOCKS_PER_IMG - 1);
    const int K   = palette_sizes[b];
    const float scale = 1.4426950408889634f / temperature[0];   // log2(e)/T

    // block-local coefficient build: thread k handles palette entry k
    {
        const int k = threadIdx.x;
        const float pr = palettes[(b * KMAX + k) * 3 + 0];
        const float pg = palettes[(b * KMAX + k) * 3 + 1];
        const float pb = palettes[(b * KMAX + k) * 3 + 2];
        float4 q;
        q.x = 2.0f * pr * scale;
        q.y = 2.0f * pg * scale;
        q.z = 2.0f * pb * scale;
        q.w = (-(pr * pr + pg * pg + pb * pb) - 3.0f) * scale;  // -3/T shift
        cc[k] = q;
    }
    __syncthreads();

    const int pix0 = (blk * THREADS + threadIdx.x) * PX;
    const long base = (long)b * (HW * 3) + (long)pix0 * 3;      // 48B aligned
    const float4 v0 = *(const float4*)(images + base + 0);
    const float4 v1 = *(const float4*)(images + base + 4);
    const float4 v2 = *(const float4*)(images + base + 8);

    const float xA0 = v0.x, xA1 = v0.y, xA2 = v0.z;
    const float xB0 = v0.w, xB1 = v1.x, xB2 = v1.y;
    const float xC0 = v1.z, xC1 = v1.w, xC2 = v2.x;
    const float xD0 = v2.y, xD1 = v2.z, xD2 = v2.w;

    float sA = 0.f, aA0 = 0.f, aA1 = 0.f, aA2 = 0.f;
    float sB = 0.f, aB0 = 0.f, aB1 = 0.f, aB2 = 0.f;
    float sC = 0.f, aC0 = 0.f, aC1 = 0.f, aC2 = 0.f;
    float sD = 0.f, aD0 = 0.f, aD1 = 0.f, aD2 = 0.f;

    #pragma unroll 2
    for (int k = 0; k < K; ++k) {
        const float4 A = cc[k];   // broadcast ds_read_b128, conflict-free
        const float lA = fmaf(A.x, xA0, fmaf(A.y, xA1, fmaf(A.z, xA2, A.w)));
        const float lB = fmaf(A.x, xB0, fmaf(A.y, xB1, fmaf(A.z, xB2, A.w)));
        const float lC = fmaf(A.x, xC0, fmaf(A.y, xC1, fmaf(A.z, xC2, A.w)));
        const float lD = fmaf(A.x, xD0, fmaf(A.y, xD1, fmaf(A.z, xD2, A.w)));
        const float wA = exp2f(lA), wB = exp2f(lB), wC = exp2f(lC), wD = exp2f(lD);
        sA += wA; aA0 = fmaf(wA, A.x, aA0); aA1 = fmaf(wA, A.y, aA1); aA2 = fmaf(wA, A.z, aA2);
        sB += wB; aB0 = fmaf(wB, A.x, aB0); aB1 = fmaf(wB, A.y, aB1); aB2 = fmaf(wB, A.z, aB2);
        sC += wC; aC0 = fmaf(wC, A.x, aC0); aC1 = fmaf(wC, A.y, aC1); aC2 = fmaf(wC, A.z, aC2);
        sD += wD; aD0 = fmaf(wD, A.x, aD0); aD1 = fmaf(wD, A.y, aD1); aD2 = fmaf(wD, A.z, aD2);
    }

    const float h = 0.5f / scale;                 // undo a = 2*scale*p
    const float iA = h / sA, iB = h / sB, iC = h / sC, iD = h / sD;

    float4 o0, o1, o2;
    o0.x = aA0 * iA; o0.y = aA1 * iA; o0.z = aA2 * iA;
    o0.w = aB0 * iB; o1.x = aB1 * iB; o1.y = aB2 * iB;
    o1.z = aC0 * iC; o1.w = aC1 * iC; o2.x = aC2 * iC;
    o2.y = aD0 * iD; o2.z = aD1 * iD; o2.w = aD2 * iD;

    *(float4*)(out + base + 0) = o0;
    *(float4*)(out + base + 4) = o1;
    *(float4*)(out + base + 8) = o2;
}

extern "C" void kernel_launch(void* const* d_in, const int* in_sizes, int n_in,
                              void* d_out, int out_size, void* d_ws, size_t ws_size,
                              hipStream_t stream) {
    const float* images        = (const float*)d_in[0];
    const float* palettes      = (const float*)d_in[1];
    const int*   palette_sizes = (const int*)d_in[2];
    const float* temperature   = (const float*)d_in[3];
    float*       out           = (float*)d_out;

    palette_blend_kernel<<<dim3(BATCH * BLOCKS_PER_IMG), dim3(THREADS), 0, stream>>>(
        images, palettes, palette_sizes, temperature, out);
}